// Round 5
// baseline (225.304 us; speedup 1.0000x reference)
//
#include <hip/hip_runtime.h>

typedef float v2f __attribute__((ext_vector_type(2)));

constexpr int DIM = 6;
constexpr float NEG = 0.01f;

// One 6x6 layer on 2 packed rows (v_pk_* ops). Weights uniform -> SGPR,
// broadcast into both pk halves via op_sel (no per-weight movs).
template<bool RELU>
__device__ __forceinline__ void layer2(const float* __restrict__ W,
                                       const float* __restrict__ b,
                                       v2f (&x)[DIM]) {
    v2f y[DIM];
    #pragma unroll
    for (int j = 0; j < DIM; ++j) {
        const float bj = b[j];
        v2f acc = {bj, bj};
        #pragma unroll
        for (int k = 0; k < DIM; ++k) {
            const float wjk = W[j * DIM + k];
            acc = __builtin_elementwise_fma((v2f){wjk, wjk}, x[k], acc);
        }
        y[j] = RELU ? __builtin_elementwise_max(acc, acc * (v2f){NEG, NEG}) : acc;
    }
    #pragma unroll
    for (int j = 0; j < DIM; ++j) x[j] = y[j];
}

__device__ __forceinline__ void run_net(const float* __restrict__ Ws,
                                        const float* __restrict__ bs,
                                        v2f (&w)[DIM]) {
    #pragma unroll 1
    for (int blk = 0; blk < 4; ++blk) {
        const float* Wb = Ws + (size_t)blk * 4 * 36;
        const float* bb = bs + (size_t)blk * 4 * 6;
        v2f res[DIM];
        #pragma unroll
        for (int k = 0; k < DIM; ++k) res[k] = w[k];
        layer2<true >(Wb +   0, bb +  0, w);
        layer2<true >(Wb +  36, bb +  6, w);
        layer2<true >(Wb +  72, bb + 12, w);
        layer2<false>(Wb + 108, bb + 18, w);
        #pragma unroll
        for (int k = 0; k < DIM; ++k) w[k] += res[k];
    }
    layer2<true >(Ws + 16 * 36, bs + 16 * 6, w);
    layer2<true >(Ws + 17 * 36, bs + 17 * 6, w);
    layer2<false>(Ws + 18 * 36, bs + 18 * 6, w);
}

__device__ __forceinline__ void compute_store(
    const float4& a, const float4& b, const float4& c,
    const float (&sc)[DIM], const float (&sh)[DIM],
    const float* __restrict__ Ws, const float* __restrict__ bs,
    float* __restrict__ op)
{
    v2f w[DIM] = {{a.x, b.z}, {a.y, b.w}, {a.z, c.x},
                  {a.w, c.y}, {b.x, c.z}, {b.y, c.w}};
    #pragma unroll
    for (int k = 0; k < DIM; ++k)
        w[k] = __builtin_elementwise_fma(w[k], (v2f){sc[k], sc[k]},
                                               (v2f){sh[k], sh[k]});
    run_net(Ws, bs, w);
    float4 o0 = {w[0].x, w[1].x, w[2].x, w[3].x};
    float4 o1 = {w[4].x, w[5].x, w[0].y, w[1].y};
    float4 o2 = {w[2].y, w[3].y, w[4].y, w[5].y};
    *reinterpret_cast<float4*>(op + 0) = o0;
    *reinterpret_cast<float4*>(op + 4) = o1;
    *reinterpret_cast<float4*>(op + 8) = o2;
}

// Fast path: B divisible by 2*T. Grid-stride, next-x prefetched before compute.
__global__ __launch_bounds__(256, 6) void mlp19_strided(
    const float* __restrict__ X,
    const float* __restrict__ Ws,
    const float* __restrict__ bs,
    const float* __restrict__ bounds,
    float* __restrict__ out, int iters)
{
    const long long T = (long long)gridDim.x * blockDim.x;
    const long long g = (long long)blockIdx.x * blockDim.x + threadIdx.x;

    float sc[DIM], sh[DIM];
    #pragma unroll
    for (int k = 0; k < DIM; ++k) {
        const float lo = bounds[2 * k], hi = bounds[2 * k + 1];
        const float inv = 1.0f / (hi - lo);
        sc[k] = inv;
        sh[k] = -lo * inv;
    }

    const long long rstep = 2 * T;
    long long r = 2 * g;

    const float* xp = X + r * DIM;
    float4 ca = *reinterpret_cast<const float4*>(xp + 0);
    float4 cb = *reinterpret_cast<const float4*>(xp + 4);
    float4 cc = *reinterpret_cast<const float4*>(xp + 8);

    #pragma unroll 1
    for (int it = 0; it < iters - 1; ++it) {
        // prefetch next chunk BEFORE the long compute
        const float* xn = X + (r + rstep) * DIM;
        float4 na = *reinterpret_cast<const float4*>(xn + 0);
        float4 nb = *reinterpret_cast<const float4*>(xn + 4);
        float4 nc = *reinterpret_cast<const float4*>(xn + 8);

        compute_store(ca, cb, cc, sc, sh, Ws, bs, out + r * DIM);

        ca = na; cb = nb; cc = nc;
        r += rstep;
    }
    compute_store(ca, cb, cc, sc, sh, Ws, bs, out + r * DIM);
}

// Fallback: guarded, 2 rows/thread (R3 structure).
__global__ __launch_bounds__(256, 4) void mlp19_guarded(
    const float* __restrict__ X,
    const float* __restrict__ Ws,
    const float* __restrict__ bs,
    const float* __restrict__ bounds,
    float* __restrict__ out, int B)
{
    const int g  = blockIdx.x * blockDim.x + threadIdx.x;
    const int r0 = 2 * g;
    if (r0 >= B) return;
    const bool full = (r0 + 1) < B;

    float sc[DIM], sh[DIM];
    #pragma unroll
    for (int k = 0; k < DIM; ++k) {
        const float lo = bounds[2 * k], hi = bounds[2 * k + 1];
        const float inv = 1.0f / (hi - lo);
        sc[k] = inv;
        sh[k] = -lo * inv;
    }

    v2f w[DIM];
    const float* xp = X + (size_t)r0 * DIM;
    if (full) {
        const float4 a = *reinterpret_cast<const float4*>(xp + 0);
        const float4 b = *reinterpret_cast<const float4*>(xp + 4);
        const float4 c = *reinterpret_cast<const float4*>(xp + 8);
        w[0] = (v2f){a.x, b.z}; w[1] = (v2f){a.y, b.w};
        w[2] = (v2f){a.z, c.x}; w[3] = (v2f){a.w, c.y};
        w[4] = (v2f){b.x, c.z}; w[5] = (v2f){b.y, c.w};
    } else {
        #pragma unroll
        for (int k = 0; k < DIM; ++k) w[k] = (v2f){xp[k], 0.0f};
    }

    #pragma unroll
    for (int k = 0; k < DIM; ++k)
        w[k] = __builtin_elementwise_fma(w[k], (v2f){sc[k], sc[k]},
                                               (v2f){sh[k], sh[k]});

    run_net(Ws, bs, w);

    float* op = out + (size_t)r0 * DIM;
    if (full) {
        float4 o0 = {w[0].x, w[1].x, w[2].x, w[3].x};
        float4 o1 = {w[4].x, w[5].x, w[0].y, w[1].y};
        float4 o2 = {w[2].y, w[3].y, w[4].y, w[5].y};
        *reinterpret_cast<float4*>(op + 0) = o0;
        *reinterpret_cast<float4*>(op + 4) = o1;
        *reinterpret_cast<float4*>(op + 8) = o2;
    } else {
        #pragma unroll
        for (int k = 0; k < DIM; ++k) op[k] = w[k].x;
    }
}

extern "C" void kernel_launch(void* const* d_in, const int* in_sizes, int n_in,
                              void* d_out, int out_size, void* d_ws, size_t ws_size,
                              hipStream_t stream) {
    const float* X      = (const float*)d_in[0];
    const float* Ws     = (const float*)d_in[1];
    const float* bs     = (const float*)d_in[2];
    const float* bounds = (const float*)d_in[3];
    float* out = (float*)d_out;

    const long long B = in_sizes[0] / DIM;
    const int block = 256;
    const int grid_fast = 2048;                       // 8 blocks/CU x 256 CUs
    const long long rows_per_iter = 2LL * grid_fast * block;

    if (B >= rows_per_iter && (B % rows_per_iter) == 0) {
        const int iters = (int)(B / rows_per_iter);
        hipLaunchKernelGGL(mlp19_strided, dim3(grid_fast), dim3(block), 0, stream,
                           X, Ws, bs, bounds, out, iters);
    } else {
        const int grid = (int)((B + 2LL * block - 1) / (2LL * block));
        hipLaunchKernelGGL(mlp19_guarded, dim3(grid), dim3(block), 0, stream,
                           X, Ws, bs, bounds, out, (int)B);
    }
}

// Round 6
// 207.338 us; speedup vs baseline: 1.0867x; 1.0867x over previous
//
#include <hip/hip_runtime.h>

typedef float v2f __attribute__((ext_vector_type(2)));

constexpr int DIM = 6;
constexpr float NEG = 0.01f;

// One 6x6 layer on 4 rows held as two packed pk-pairs (v_pk_* ops).
// Weights/bias wave-uniform -> SGPR; each weight feeds both pairs (2 pk_fma
// per s_load'ed word). FOLD_RES starts the accumulator at res+bias, fusing
// the residual add into the block-end layer.
template<bool RELU, bool FOLD_RES>
__device__ __forceinline__ void layer4(const float* __restrict__ W,
                                       const float* __restrict__ b,
                                       v2f (&x)[2][DIM],
                                       const v2f (&res)[2][DIM]) {
    v2f y0[DIM], y1[DIM];
    #pragma unroll
    for (int j = 0; j < DIM; ++j) {
        const float bj = b[j];
        v2f a0, a1;
        if (FOLD_RES) {
            a0 = res[0][j] + (v2f){bj, bj};
            a1 = res[1][j] + (v2f){bj, bj};
        } else {
            a0 = (v2f){bj, bj};
            a1 = (v2f){bj, bj};
        }
        #pragma unroll
        for (int k = 0; k < DIM; ++k) {
            const float wjk = W[j * DIM + k];
            a0 = __builtin_elementwise_fma((v2f){wjk, wjk}, x[0][k], a0);
            a1 = __builtin_elementwise_fma((v2f){wjk, wjk}, x[1][k], a1);
        }
        if (RELU) {
            a0 = __builtin_elementwise_max(a0, a0 * (v2f){NEG, NEG});
            a1 = __builtin_elementwise_max(a1, a1 * (v2f){NEG, NEG});
        }
        y0[j] = a0; y1[j] = a1;
    }
    #pragma unroll
    for (int j = 0; j < DIM; ++j) { x[0][j] = y0[j]; x[1][j] = y1[j]; }
}

__device__ __forceinline__ void run_net4(const float* __restrict__ Ws,
                                         const float* __restrict__ bs,
                                         v2f (&w)[2][DIM]) {
    #pragma unroll 1
    for (int blk = 0; blk < 4; ++blk) {
        const float* Wb = Ws + (size_t)blk * 144;
        const float* bb = bs + (size_t)blk * 24;
        v2f res[2][DIM];
        #pragma unroll
        for (int p = 0; p < 2; ++p)
            #pragma unroll
            for (int k = 0; k < DIM; ++k) res[p][k] = w[p][k];
        layer4<true , false>(Wb +   0, bb +  0, w, res);
        layer4<true , false>(Wb +  36, bb +  6, w, res);
        layer4<true , false>(Wb +  72, bb + 12, w, res);
        layer4<false, true >(Wb + 108, bb + 18, w, res);   // acc = res + b
    }
    layer4<true , false>(Ws + 16 * 36, bs + 16 * 6, w, w);
    layer4<true , false>(Ws + 17 * 36, bs + 17 * 6, w, w);
    layer4<false, false>(Ws + 18 * 36, bs + 18 * 6, w, w);
}

__global__ __launch_bounds__(256, 4) void mlp19_kernel(
    const float* __restrict__ X,
    const float* __restrict__ Ws,
    const float* __restrict__ bs,
    const float* __restrict__ bounds,
    float* __restrict__ out, int B)
{
    const int g  = blockIdx.x * blockDim.x + threadIdx.x;
    const int r0 = 4 * g;
    if (r0 >= B) return;

    // normalization: w = x*sc + sh (uniform -> SGPR)
    float sc[DIM], sh[DIM];
    #pragma unroll
    for (int k = 0; k < DIM; ++k) {
        const float lo = bounds[2 * k], hi = bounds[2 * k + 1];
        const float inv = 1.0f / (hi - lo);
        sc[k] = inv;
        sh[k] = -lo * inv;
    }

    if (r0 + 3 < B) {
        const float* xp = X + (size_t)r0 * DIM;   // 24 contiguous floats
        const float4 q0 = *reinterpret_cast<const float4*>(xp +  0);
        const float4 q1 = *reinterpret_cast<const float4*>(xp +  4);
        const float4 q2 = *reinterpret_cast<const float4*>(xp +  8);
        const float4 q3 = *reinterpret_cast<const float4*>(xp + 12);
        const float4 q4 = *reinterpret_cast<const float4*>(xp + 16);
        const float4 q5 = *reinterpret_cast<const float4*>(xp + 20);

        v2f w[2][DIM];
        w[0][0] = (v2f){q0.x, q1.z}; w[0][1] = (v2f){q0.y, q1.w};
        w[0][2] = (v2f){q0.z, q2.x}; w[0][3] = (v2f){q0.w, q2.y};
        w[0][4] = (v2f){q1.x, q2.z}; w[0][5] = (v2f){q1.y, q2.w};
        w[1][0] = (v2f){q3.x, q4.z}; w[1][1] = (v2f){q3.y, q4.w};
        w[1][2] = (v2f){q3.z, q5.x}; w[1][3] = (v2f){q3.w, q5.y};
        w[1][4] = (v2f){q4.x, q5.z}; w[1][5] = (v2f){q4.y, q5.w};

        #pragma unroll
        for (int p = 0; p < 2; ++p)
            #pragma unroll
            for (int k = 0; k < DIM; ++k)
                w[p][k] = __builtin_elementwise_fma(
                    w[p][k], (v2f){sc[k], sc[k]}, (v2f){sh[k], sh[k]});

        run_net4(Ws, bs, w);

        float* op = out + (size_t)r0 * DIM;
        float4 o0 = {w[0][0].x, w[0][1].x, w[0][2].x, w[0][3].x};
        float4 o1 = {w[0][4].x, w[0][5].x, w[0][0].y, w[0][1].y};
        float4 o2 = {w[0][2].y, w[0][3].y, w[0][4].y, w[0][5].y};
        float4 o3 = {w[1][0].x, w[1][1].x, w[1][2].x, w[1][3].x};
        float4 o4 = {w[1][4].x, w[1][5].x, w[1][0].y, w[1][1].y};
        float4 o5 = {w[1][2].y, w[1][3].y, w[1][4].y, w[1][5].y};
        *reinterpret_cast<float4*>(op +  0) = o0;
        *reinterpret_cast<float4*>(op +  4) = o1;
        *reinterpret_cast<float4*>(op +  8) = o2;
        *reinterpret_cast<float4*>(op + 12) = o3;
        *reinterpret_cast<float4*>(op + 16) = o4;
        *reinterpret_cast<float4*>(op + 20) = o5;
    } else {
        // tail: per-row (at most 3 rows, one thread)
        for (int r = r0; r < B; ++r) {
            const float* xp = X + (size_t)r * DIM;
            v2f w[2][DIM];
            #pragma unroll
            for (int k = 0; k < DIM; ++k) {
                const float t = fmaf(xp[k], sc[k], sh[k]);
                w[0][k] = (v2f){t, t};
                w[1][k] = (v2f){t, t};
            }
            run_net4(Ws, bs, w);
            float* op = out + (size_t)r * DIM;
            #pragma unroll
            for (int k = 0; k < DIM; ++k) op[k] = w[0][k].x;
        }
    }
}

extern "C" void kernel_launch(void* const* d_in, const int* in_sizes, int n_in,
                              void* d_out, int out_size, void* d_ws, size_t ws_size,
                              hipStream_t stream) {
    const float* X      = (const float*)d_in[0];
    const float* Ws     = (const float*)d_in[1];
    const float* bs     = (const float*)d_in[2];
    const float* bounds = (const float*)d_in[3];
    float* out = (float*)d_out;

    const int B = in_sizes[0] / DIM;
    const int block = 256;
    const int rows_per_block = block * 4;
    const int grid = (B + rows_per_block - 1) / rows_per_block;
    hipLaunchKernelGGL(mlp19_kernel, dim3(grid), dim3(block), 0, stream,
                       X, Ws, bs, bounds, out, B);
}